// Round 1
// 1965.198 us; speedup vs baseline: 4.7689x; 4.7689x over previous
//
#include <hip/hip_runtime.h>

// ---------------------------------------------------------------------------
// Seq2Seq LSTM (B=16, H=256, L=2, S=128, T=128, V=32000).
// Inputs fp32 (per reference dtypes), output fp32. Internal compute: bf16 MFMA
// with fp32 accumulation; h and Whh use hi/lo bf16 splits for fp32-class
// accuracy in the recurrence.
// Pipeline:
//   whh_split x4 -> gathers -> [GEMM P=X@Wih^T+b -> lstm_recur] x4
//   -> attn projections -> fused score/softmax/ctx -> logits GEMM + zero_t0.
// Bulk scratch lives inside d_out (fully overwritten at the end);
// d_ws holds only Acat + flags + cfin (~2.1 MB).
//
// Cross-block recurrence sync (v2, lean): relaxed-only agent-scope atomics.
//  - h transported as ONE packed uint (bf16 hi<<16 | bf16 lo) per element,
//    written once by the producer (readers just unpack).
//  - writer: relaxed atomic h stores -> s_waitcnt vmcnt(0) -> barrier ->
//    relaxed store of per-block monotonic slot counter (no RMW contention).
//  - reader: lanes 0..15 poll the 16 slots with one wave-wide relaxed load
//    per iteration; sched_barrier(0) pins h loads after the poll.
//  No ACQUIRE/RELEASE/threadfence => no buffer_inv / buffer_wbl2 L2-wide
//  maintenance ops in the 127-step spin loops (these dominated v1's 17.7
//  us/step). Agent-scope atomics bypass L1/L2 to the coherence point, and
//  all 16 workers additionally share XCD0's L2 via the blockIdx%8==0 trick.
// ---------------------------------------------------------------------------

typedef __attribute__((ext_vector_type(8))) short s8v;
typedef __attribute__((ext_vector_type(8))) __bf16 bf8v;
typedef __attribute__((ext_vector_type(4))) float f4v;

#define HDIM 256
#define DLEN 127
#define NVOC 32000

__device__ __forceinline__ float bf2f(unsigned short u) {
  union { unsigned int i; float f; } v; v.i = ((unsigned int)u) << 16; return v.f;
}
__device__ __forceinline__ unsigned short f2bf(float x) {
  union { float f; unsigned int i; } v; v.f = x;
  unsigned int u = v.i;
  return (unsigned short)((u + 0x7FFFu + ((u >> 16) & 1u)) >> 16);
}
__device__ __forceinline__ float sigm(float x) {
  x = fminf(fmaxf(x, -30.f), 30.f);
  return 1.f / (1.f + __expf(-x));
}
__device__ __forceinline__ float tanh_f(float x) {
  float y = fminf(fmaxf(x, -15.f), 15.f);
  float e = __expf(2.f * y);
  return (e - 1.f) / (e + 1.f);
}
__device__ __forceinline__ f4v mfma_bf16(s8v a, s8v b, f4v c) {
  return __builtin_amdgcn_mfma_f32_16x16x32_bf16(
      __builtin_bit_cast(bf8v, a), __builtin_bit_cast(bf8v, b), c, 0, 0, 0);
}

// ---------------- split fp32 weight matrix into bf16 hi + lo ----------------
__global__ __launch_bounds__(256) void whh_split(
    const float* __restrict__ W, unsigned short* __restrict__ Hh,
    unsigned short* __restrict__ Hl) {
  int i = blockIdx.x * 256 + threadIdx.x;      // grid 1024 -> 262144
  float w = W[i];
  unsigned short h = f2bf(w);
  Hh[i] = h;
  Hl[i] = f2bf(w - bf2f(h));
}

// ---------------- embedding gather: fp32 emb -> bf16 rows ----------------
__global__ __launch_bounds__(64) void gather_rows(
    const int* __restrict__ toks, const float* __restrict__ emb,
    unsigned short* __restrict__ out, int dec) {
  int r = blockIdx.x, tid = threadIdx.x;
  int token = dec ? toks[(r / DLEN) * 128 + (r % DLEN)] : toks[r];
  float4 v = *(const float4*)&emb[(long)token * HDIM + tid * 4];
  unsigned short q[4] = {f2bf(v.x), f2bf(v.y), f2bf(v.z), f2bf(v.w)};
  *(uint2*)&out[(long)r * HDIM + tid * 4] = *(uint2*)q;
}

// ---------------- zero first timestep of output (fp32) ----------------
__global__ __launch_bounds__(256) void zero_t0(float* __restrict__ out) {
  int i = blockIdx.x * 256 + threadIdx.x;      // grid 500 -> 128000
  int b = i / 8000, off = (i - b * 8000) * 4;
  float4 z = {0.f, 0.f, 0.f, 0.f};
  *(float4*)&out[(long)b * 128 * NVOC + off] = z;
}

// ---------------- GEMM: C = A(MxK,bf16) @ B(NxK,fp32)^T + bias ----------------
// mode 0: fp32 out Cf (ldc). mode 1: fp32 out, row m -> row (m/Tl)*128+(m%Tl)+1.
// Loops miters m-tiles per block: m0 = (blockIdx.y*miters + mi)*128.
__global__ __launch_bounds__(256) void gemm_bt(
    const unsigned short* __restrict__ A, int lda,
    const float* __restrict__ B, int ldb,
    int M, int K,
    const float* __restrict__ bias1, const float* __restrict__ bias2,
    float* __restrict__ Cf, int ldc, int mode, int Tl, int miters) {
  __shared__ unsigned short As[128 * 40];
  __shared__ unsigned short Bs[128 * 40];
  int tid = threadIdx.x;
  int lane = tid & 63, wid = tid >> 6;
  int wm = (wid >> 1) * 64, wn = (wid & 1) * 64;
  int r16 = lane & 15, kg = lane >> 4;
  int n0 = blockIdx.x * 128;

  for (int mi = 0; mi < miters; mi++) {
    int m0 = (blockIdx.y * miters + mi) * 128;
    f4v acc[4][4];
    for (int i = 0; i < 4; i++)
      for (int j = 0; j < 4; j++) acc[i][j] = (f4v){0.f, 0.f, 0.f, 0.f};

    for (int k0 = 0; k0 < K; k0 += 32) {
      for (int i = 0; i < 2; i++) {
        int idx = tid + i * 256;
        int row = idx >> 2, kc = (idx & 3) * 8;
        uint4 va = {0u, 0u, 0u, 0u};
        int gm = m0 + row;
        if (gm < M) va = *(const uint4*)&A[(long)gm * lda + k0 + kc];
        *(uint4*)&As[row * 40 + kc] = va;
        const float* bp = &B[(long)(n0 + row) * ldb + k0 + kc];
        float4 b0 = *(const float4*)bp, b1 = *(const float4*)(bp + 4);
        unsigned short q[8] = {f2bf(b0.x), f2bf(b0.y), f2bf(b0.z), f2bf(b0.w),
                               f2bf(b1.x), f2bf(b1.y), f2bf(b1.z), f2bf(b1.w)};
        *(uint4*)&Bs[row * 40 + kc] = *(uint4*)q;
      }
      __syncthreads();
      s8v af[4], bfg[4];
      for (int f = 0; f < 4; f++) {
        af[f]  = *(const s8v*)&As[(wm + f * 16 + r16) * 40 + kg * 8];
        bfg[f] = *(const s8v*)&Bs[(wn + f * 16 + r16) * 40 + kg * 8];
      }
      for (int i = 0; i < 4; i++)
        for (int j = 0; j < 4; j++)
          acc[i][j] = mfma_bf16(af[i], bfg[j], acc[i][j]);
      __syncthreads();
    }

    int rbase = (lane >> 4) * 4;
    for (int j = 0; j < 4; j++) {
      int n = n0 + wn + j * 16 + r16;
      float bv = 0.f;
      if (bias1) bv += bias1[n];
      if (bias2) bv += bias2[n];
      for (int i = 0; i < 4; i++) {
        for (int r = 0; r < 4; r++) {
          int m = m0 + wm + i * 16 + rbase + r;
          if (m < M) {
            float v = acc[i][j][r] + bv;
            if (mode == 0) {
              Cf[(long)m * ldc + n] = v;
            } else {
              int bb = m / Tl, tt = m - bb * Tl;
              Cf[(long)(bb * 128 + tt + 1) * ldc + n] = v;
            }
          }
        }
      }
    }
    __syncthreads();
  }
}

// ---------------- LSTM recurrence ----------------
// grid 121; workers at blockIdx%8==0 (16). Worker blk owns units [blk*16,+16).
// Wave g computes gate g for 16 units x 16 batches via MFMA; Whh hi/lo
// fragments persistent in VGPRs (3-term product with h hi/lo split, three
// independent accumulator chains).
// hsync element = packed uint: bf16(h) in hi 16 bits, bf16(h - hi) in lo.
// slots[blk] = number of completed steps of block blk (monotonic, zeroed
// once per launch). All cross-block traffic is RELAXED agent-scope atomics;
// release ordering is enforced by an explicit s_waitcnt vmcnt(0) before the
// slot store (no buffer_inv / buffer_wbl2 cache maintenance anywhere).
__global__ __launch_bounds__(256) void lstm_recur(
    const float* __restrict__ P,              // [16*Tl][1024], rows b*Tl+t
    const unsigned short* __restrict__ WhhH,  // [1024][256] bf16 hi
    const unsigned short* __restrict__ WhhL,  // [1024][256] bf16 lo
    unsigned int* __restrict__ hsync,         // [Tl][16][256] packed hi|lo
    int* __restrict__ slots,                  // [16] per-block step counters
    const unsigned int* __restrict__ hinit,   // [16][256] packed, or null
    const float* __restrict__ cinit,          // [16][256] or null
    unsigned short* __restrict__ hout, int ldo, int coloff,
    float* __restrict__ cfin, int Tl) {
  int widx = (int)blockIdx.x;
  if (widx & 7) return;                       // keep workers on XCD0 (L2 share)
  int blk = widx >> 3;                        // 0..15
  __shared__ unsigned short hh[16 * 264];
  __shared__ unsigned short hl[16 * 264];
  __shared__ float gbuf[4][16][16];
  int tid = threadIdx.x;
  int lane = tid & 63, gate = tid >> 6;
  int U = blk * 16;
  int r16 = lane & 15, kg = lane >> 4;

  s8v wfh[8], wfl[8];
  {
    long roff = (long)(gate * 256 + U + r16) * 256 + kg * 8;
    for (int kt = 0; kt < 8; kt++) {
      wfh[kt] = *(const s8v*)(WhhH + roff + kt * 32);
      wfl[kt] = *(const s8v*)(WhhL + roff + kt * 32);
    }
  }
  int b = tid >> 4, u = tid & 15;
  float c = cinit ? cinit[b * 256 + U + u] : 0.f;

  for (int t = 0; t < Tl; t++) {
    if (t > 0) {
      // ---- wait for all 16 producers of step t-1 (relaxed poll) ----
      if (tid < 16) {
        while (__hip_atomic_load(slots + tid, __ATOMIC_RELAXED,
                                 __HIP_MEMORY_SCOPE_AGENT) < t) {}
      }
      __syncthreads();
      __builtin_amdgcn_sched_barrier(0);      // pin h loads after the poll
      const unsigned int* hp = hsync + (size_t)(t - 1) * 4096;
      unsigned int uv[16];
#pragma unroll
      for (int i = 0; i < 16; i++)
        uv[i] = __hip_atomic_load(hp + i * 256 + tid, __ATOMIC_RELAXED,
                                  __HIP_MEMORY_SCOPE_AGENT);
#pragma unroll
      for (int i = 0; i < 16; i++) {
        hh[i * 264 + tid] = (unsigned short)(uv[i] >> 16);
        hl[i * 264 + tid] = (unsigned short)(uv[i] & 0xFFFFu);
      }
    } else {
      for (int i = 0; i < 16; i++) {
        unsigned int uvv = hinit ? hinit[i * 256 + tid] : 0u;
        hh[i * 264 + tid] = (unsigned short)(uvv >> 16);
        hl[i * 264 + tid] = (unsigned short)(uvv & 0xFFFFu);
      }
    }
    const float* prow = P + (size_t)(b * Tl + t) * 1024 + U + u;
    float p0 = prow[0], p1 = prow[256], p2 = prow[512], p3 = prow[768];
    __syncthreads();
    // three independent accumulator chains (ah*Wh, al*Wh, ah*Wl)
    f4v a0 = (f4v){0.f, 0.f, 0.f, 0.f};
    f4v a1 = (f4v){0.f, 0.f, 0.f, 0.f};
    f4v a2 = (f4v){0.f, 0.f, 0.f, 0.f};
#pragma unroll
    for (int kt = 0; kt < 8; kt++) {
      s8v ah = *(const s8v*)&hh[r16 * 264 + kt * 32 + kg * 8];
      s8v al = *(const s8v*)&hl[r16 * 264 + kt * 32 + kg * 8];
      a0 = mfma_bf16(ah, wfh[kt], a0);
      a1 = mfma_bf16(al, wfh[kt], a1);
      a2 = mfma_bf16(ah, wfl[kt], a2);
    }
#pragma unroll
    for (int r = 0; r < 4; r++)
      gbuf[gate][kg * 4 + r][r16] = a0[r] + a1[r] + a2[r];
    __syncthreads();
    float gi = gbuf[0][b][u] + p0;
    float gf = gbuf[1][b][u] + p1;
    float gg = gbuf[2][b][u] + p2;
    float go = gbuf[3][b][u] + p3;
    c = sigm(gf) * c + sigm(gi) * tanh_f(gg);
    float h = sigm(go) * tanh_f(c);
    unsigned short hb = f2bf(h);
    unsigned int packed =
        ((unsigned int)hb << 16) | (unsigned int)f2bf(h - bf2f(hb));
    __hip_atomic_store(hsync + (size_t)t * 4096 + b * 256 + U + u, packed,
                       __ATOMIC_RELAXED, __HIP_MEMORY_SCOPE_AGENT);
    hout[(size_t)(b * Tl + t) * ldo + coloff + U + u] = hb;
    // release: h stores acked at the coherence point before the flag store
    asm volatile("s_waitcnt vmcnt(0)" ::: "memory");
    __syncthreads();
    if (tid == 0)
      __hip_atomic_store(slots + blk, t + 1, __ATOMIC_RELAXED,
                         __HIP_MEMORY_SCOPE_AGENT);
  }
  if (cfin) cfin[b * 256 + U + u] = c;
}

// ---------------- attention: scores + softmax + context ----------------
__global__ __launch_bounds__(256) void attn_ctx(
    const float* __restrict__ dp,             // [2032][256] (includes attn_b)
    const float* __restrict__ ep,             // [2048][256]
    const float* __restrict__ vw,             // [256]
    const unsigned int* __restrict__ enc_out, // [128][16][256] packed hi|lo
    unsigned short* __restrict__ Acat)        // [2032][512], write cols 256..511
{
  __shared__ float sdp[256], sv[256], sc[128];
  int bt = blockIdx.x;
  int b = bt / DLEN;
  int tid = threadIdx.x;
  sdp[tid] = dp[(long)bt * 256 + tid];
  sv[tid] = vw[tid];
  __syncthreads();
  int lane = tid & 63, wid = tid >> 6;
  for (int i = 0; i < 32; i++) {
    int s = wid * 32 + i;
    float4 e4 = *(const float4*)&ep[(long)(b * 128 + s) * 256 + lane * 4];
    int h0 = lane * 4;
    float part = sv[h0] * tanh_f(sdp[h0] + e4.x);
    part += sv[h0 + 1] * tanh_f(sdp[h0 + 1] + e4.y);
    part += sv[h0 + 2] * tanh_f(sdp[h0 + 2] + e4.z);
    part += sv[h0 + 3] * tanh_f(sdp[h0 + 3] + e4.w);
    for (int off = 32; off >= 1; off >>= 1) part += __shfl_xor(part, off);
    if (lane == 0) sc[s] = part;
  }
  __syncthreads();
  if (wid == 0) {
    float a0 = sc[lane], a1 = sc[lane + 64];
    float mx = fmaxf(a0, a1);
    for (int off = 32; off >= 1; off >>= 1) mx = fmaxf(mx, __shfl_xor(mx, off));
    float e0 = __expf(a0 - mx), e1 = __expf(a1 - mx);
    float sm = e0 + e1;
    for (int off = 32; off >= 1; off >>= 1) sm += __shfl_xor(sm, off);
    float inv = 1.0f / sm;
    sc[lane] = e0 * inv;
    sc[lane + 64] = e1 * inv;
  }
  __syncthreads();
  float acc = 0.f;
  for (int s = 0; s < 128; s++) {
    unsigned int uv = enc_out[(long)(s * 16 + b) * 256 + tid];
    float hv = bf2f((unsigned short)(uv >> 16)) +
               bf2f((unsigned short)(uv & 0xFFFFu));
    acc += sc[s] * hv;
  }
  Acat[(long)bt * 512 + 256 + tid] = f2bf(acc);
}

// ---------------------------------------------------------------------------
extern "C" void kernel_launch(void* const* d_in, const int* in_sizes, int n_in,
                              void* d_out, int out_size, void* d_ws, size_t ws_size,
                              hipStream_t stream) {
  (void)in_sizes; (void)n_in; (void)out_size; (void)ws_size;
  const int* src = (const int*)d_in[0];
  const int* tgt = (const int*)d_in[1];
  auto F32 = [&](int i) { return (const float*)d_in[i]; };
  const float* enc_emb = F32(2);
  const float* dec_emb = F32(3);
  // enc l0: 4..7 (Wih,Whh,bih,bhh), enc l1: 8..11, dec l0: 12..15, dec l1: 16..19
  const float* attnW = F32(20);
  const float* attnB = F32(21);
  const float* vw = F32(22);
  const float* outW = F32(23);
  const float* outB = F32(24);
  float* out = (float*)d_out;

  // ---- bulk scratch inside d_out (dead before final logits/zero writes) ----
  float* Pf  = out;                        // 2,097,152 f
  unsigned int* hs0 = (unsigned int*)(Pf + 2097152);  // 524,288 u32 each
  unsigned int* hs1 = hs0 + 524288;
  unsigned int* hs2 = hs1 + 524288;
  unsigned int* hs3 = hs2 + 524288;
  float* dpf = (float*)(hs3 + 524288);     // 524,288 f (uses 520,192)
  float* epf = dpf + 524288;               // 524,288 f
  unsigned short* WHB = (unsigned short*)(epf + 524288);  // 8 x 262,144 shorts
  unsigned short* WhhH[4], *WhhL[4];
  for (int l = 0; l < 4; l++) {
    WhhH[l] = WHB + (size_t)l * 524288;
    WhhL[l] = WHB + (size_t)l * 524288 + 262144;
  }
  unsigned short* XB = WHB + (size_t)4 * 524288;          // 5 x 524,288 shorts
  unsigned short* Xe  = XB;
  unsigned short* X2  = XB + 524288;
  unsigned short* Xd  = XB + 2 * 524288;
  unsigned short* Xd2 = XB + 3 * 524288;
  unsigned short* Ebf = XB + 4 * 524288;
  // total: ~7.6M floats = 30.4 MB << 65.5M floats of d_out

  // ---- minimal d_ws usage (live during logits GEMM) ----
  char* w = (char*)d_ws;
  unsigned short* Acat = (unsigned short*)w;              // 2,080,768 B
  int* arrAll = (int*)(w + 2097152);                      // 4*128*4 B
  float* cfin = (float*)(w + 2097152 + 4096);             // 2*4096*4 B
  int* arr0 = arrAll, *arr1 = arrAll + 128, *arr2 = arrAll + 256,
     * arr3 = arrAll + 384;
  float* cfin0 = cfin, *cfin1 = cfin + 4096;

  hipMemsetAsync(arrAll, 0, 4096, stream);
  // weight hi/lo splits (Whh of the 4 layer-runs: in[5],[9],[13],[17])
  whh_split<<<1024, 256, 0, stream>>>(F32(5),  WhhH[0], WhhL[0]);
  whh_split<<<1024, 256, 0, stream>>>(F32(9),  WhhH[1], WhhL[1]);
  whh_split<<<1024, 256, 0, stream>>>(F32(13), WhhH[2], WhhL[2]);
  whh_split<<<1024, 256, 0, stream>>>(F32(17), WhhH[3], WhhL[3]);
  gather_rows<<<2048, 64, 0, stream>>>(src, enc_emb, Xe, 0);
  gather_rows<<<2032, 64, 0, stream>>>(tgt, dec_emb, Xd, 1);
  // encoder layer 0
  gemm_bt<<<dim3(8, 16), 256, 0, stream>>>(Xe, 256, F32(4), 256, 2048, 256,
      F32(6), F32(7), Pf, 1024, 0, 0, 1);
  lstm_recur<<<121, 256, 0, stream>>>(Pf, WhhH[0], WhhL[0], hs0, arr0,
      nullptr, nullptr, X2, 256, 0, cfin0, 128);
  // encoder layer 1
  gemm_bt<<<dim3(8, 16), 256, 0, stream>>>(X2, 256, F32(8), 256, 2048, 256,
      F32(10), F32(11), Pf, 1024, 0, 0, 1);
  lstm_recur<<<121, 256, 0, stream>>>(Pf, WhhH[1], WhhL[1], hs1, arr1,
      nullptr, nullptr, Ebf, 256, 0, cfin1, 128);
  // decoder layer 0 (init = enc layer0 finals)
  gemm_bt<<<dim3(8, 16), 256, 0, stream>>>(Xd, 256, F32(12), 256, 2032, 256,
      F32(14), F32(15), Pf, 1024, 0, 0, 1);
  lstm_recur<<<121, 256, 0, stream>>>(Pf, WhhH[2], WhhL[2], hs2, arr2,
      hs0 + (size_t)127 * 4096, cfin0, Xd2, 256, 0, nullptr, 127);
  // decoder layer 1 (init = enc layer1 finals); h -> Acat cols 0..255
  gemm_bt<<<dim3(8, 16), 256, 0, stream>>>(Xd2, 256, F32(16), 256, 2032, 256,
      F32(18), F32(19), Pf, 1024, 0, 0, 1);
  lstm_recur<<<121, 256, 0, stream>>>(Pf, WhhH[3], WhhL[3], hs3, arr3,
      hs1 + (size_t)127 * 4096, cfin1, Acat, 512, 0, nullptr, 127);
  // attention projections: dp = dec_out@Wd^T + attn_b ; ep = enc_out@We^T
  gemm_bt<<<dim3(2, 16), 256, 0, stream>>>(Acat, 512, attnW, 512, 2032, 256,
      attnB, nullptr, dpf, 256, 0, 0, 1);
  gemm_bt<<<dim3(2, 16), 256, 0, stream>>>(Ebf, 256, attnW + 256, 512, 2048, 256,
      nullptr, nullptr, epf, 256, 0, 0, 1);
  attn_ctx<<<2032, 256, 0, stream>>>(dpf, epf, vw, hs1, Acat);
  // ---- final writes: every element of d_out is overwritten from here ----
  gemm_bt<<<dim3(250, 4), 256, 0, stream>>>(Acat, 512, outW, 512, 2032, 512,
      outB, nullptr, out, NVOC, 1, 127, 4);
  zero_t0<<<500, 256, 0, stream>>>(out);
}

// Round 3
// 1958.493 us; speedup vs baseline: 4.7852x; 1.0034x over previous
//
#include <hip/hip_runtime.h>

// ---------------------------------------------------------------------------
// Seq2Seq LSTM (B=16, H=256, L=2, S=128, T=128, V=32000).
// Inputs fp32 (per reference dtypes), output fp32. Internal compute: bf16 MFMA
// with fp32 accumulation; h and Whh use hi/lo bf16 splits for fp32-class
// accuracy in the recurrence.
// Pipeline:
//   whh_split4 -> gathers -> gemm(enc0) -> gemm(dec0, hoisted) -> lstm0 ->
//   gemm(enc1) -> lstm1 -> lstm2 -> gemm(dec1) -> lstm3
//   -> attn projections -> fused score/softmax/ctx -> logits GEMM + zero_t0.
// Bulk scratch lives inside d_out (fully overwritten at the end);
// d_ws holds only Acat + cfin (~2.1 MB).
//
// Cross-block recurrence sync (v3b, data-is-flag): hsync buffers pre-filled
// with sentinel 0xFFFFFFFF (bf16 hi of a finite h can never be 0xFFFF=NaN).
//  - producer: computes h, issues ONE relaxed agent-scope packed store
//    (bf16 hi<<16 | bf16 lo). No vmcnt wait, no flag store, no tail barrier.
//  - consumer: every thread spins on its own 16 h-words until all != sentinel;
//    the poll load IS the data load (no separate flag hop). s_sleep(1)
//    backoff only after a failed sweep (no fast-path cost).
// All workers stay on XCD0 via the blockIdx%8==0 trick (shared L2 locality;
// correctness does not depend on it — atomics go to the coherence point).
// ---------------------------------------------------------------------------

typedef __attribute__((ext_vector_type(8))) short s8v;
typedef __attribute__((ext_vector_type(8))) __bf16 bf8v;
typedef __attribute__((ext_vector_type(4))) float f4v;

#define HDIM 256
#define DLEN 127
#define NVOC 32000
#define SENTINEL 0xFFFFFFFFu

__device__ __forceinline__ float bf2f(unsigned short u) {
  union { unsigned int i; float f; } v; v.i = ((unsigned int)u) << 16; return v.f;
}
__device__ __forceinline__ unsigned short f2bf(float x) {
  union { float f; unsigned int i; } v; v.f = x;
  unsigned int u = v.i;
  return (unsigned short)((u + 0x7FFFu + ((u >> 16) & 1u)) >> 16);
}
__device__ __forceinline__ float sigm(float x) {
  x = fminf(fmaxf(x, -30.f), 30.f);
  return 1.f / (1.f + __expf(-x));
}
__device__ __forceinline__ float tanh_f(float x) {
  float y = fminf(fmaxf(x, -15.f), 15.f);
  float e = __expf(2.f * y);
  return (e - 1.f) / (e + 1.f);
}
__device__ __forceinline__ f4v mfma_bf16(s8v a, s8v b, f4v c) {
  return __builtin_amdgcn_mfma_f32_16x16x32_bf16(
      __builtin_bit_cast(bf8v, a), __builtin_bit_cast(bf8v, b), c, 0, 0, 0);
}

// ------------- split 4 fp32 weight matrices into bf16 hi + lo -------------
// grid 4096: blocks [l*1024, (l+1)*1024) handle layer-run l.
// Output layout: HB + l*524288 = hi[262144] then lo[262144].
__global__ __launch_bounds__(256) void whh_split4(
    const float* __restrict__ W0, const float* __restrict__ W1,
    const float* __restrict__ W2, const float* __restrict__ W3,
    unsigned short* __restrict__ HB) {
  int l = blockIdx.x >> 10;
  int i = (blockIdx.x & 1023) * 256 + threadIdx.x;
  const float* W = (l == 0) ? W0 : (l == 1) ? W1 : (l == 2) ? W2 : W3;
  float w = W[i];
  unsigned short h = f2bf(w);
  unsigned short* Hh = HB + (size_t)l * 524288;
  Hh[i] = h;
  Hh[262144 + i] = f2bf(w - bf2f(h));
}

// ---------------- embedding gather: fp32 emb -> bf16 rows ----------------
__global__ __launch_bounds__(64) void gather_rows(
    const int* __restrict__ toks, const float* __restrict__ emb,
    unsigned short* __restrict__ out, int dec) {
  int r = blockIdx.x, tid = threadIdx.x;
  int token = dec ? toks[(r / DLEN) * 128 + (r % DLEN)] : toks[r];
  float4 v = *(const float4*)&emb[(long)token * HDIM + tid * 4];
  unsigned short q[4] = {f2bf(v.x), f2bf(v.y), f2bf(v.z), f2bf(v.w)};
  *(uint2*)&out[(long)r * HDIM + tid * 4] = *(uint2*)q;
}

// ---------------- zero first timestep of output (fp32) ----------------
__global__ __launch_bounds__(256) void zero_t0(float* __restrict__ out) {
  int i = blockIdx.x * 256 + threadIdx.x;      // grid 500 -> 128000
  int b = i / 8000, off = (i - b * 8000) * 4;
  float4 z = {0.f, 0.f, 0.f, 0.f};
  *(float4*)&out[(long)b * 128 * NVOC + off] = z;
}

// ---------------- GEMM: C = A(MxK,bf16) @ B(NxK,fp32)^T + bias ----------------
// mode 0: fp32 out Cf (ldc). mode 1: fp32 out, row m -> row (m/Tl)*128+(m%Tl)+1.
// Loops miters m-tiles per block: m0 = (blockIdx.y*miters + mi)*128.
__global__ __launch_bounds__(256) void gemm_bt(
    const unsigned short* __restrict__ A, int lda,
    const float* __restrict__ B, int ldb,
    int M, int K,
    const float* __restrict__ bias1, const float* __restrict__ bias2,
    float* __restrict__ Cf, int ldc, int mode, int Tl, int miters) {
  __shared__ unsigned short As[128 * 40];
  __shared__ unsigned short Bs[128 * 40];
  int tid = threadIdx.x;
  int lane = tid & 63, wid = tid >> 6;
  int wm = (wid >> 1) * 64, wn = (wid & 1) * 64;
  int r16 = lane & 15, kg = lane >> 4;
  int n0 = blockIdx.x * 128;

  for (int mi = 0; mi < miters; mi++) {
    int m0 = (blockIdx.y * miters + mi) * 128;
    f4v acc[4][4];
    for (int i = 0; i < 4; i++)
      for (int j = 0; j < 4; j++) acc[i][j] = (f4v){0.f, 0.f, 0.f, 0.f};

    for (int k0 = 0; k0 < K; k0 += 32) {
      for (int i = 0; i < 2; i++) {
        int idx = tid + i * 256;
        int row = idx >> 2, kc = (idx & 3) * 8;
        uint4 va = {0u, 0u, 0u, 0u};
        int gm = m0 + row;
        if (gm < M) va = *(const uint4*)&A[(long)gm * lda + k0 + kc];
        *(uint4*)&As[row * 40 + kc] = va;
        const float* bp = &B[(long)(n0 + row) * ldb + k0 + kc];
        float4 b0 = *(const float4*)bp, b1 = *(const float4*)(bp + 4);
        unsigned short q[8] = {f2bf(b0.x), f2bf(b0.y), f2bf(b0.z), f2bf(b0.w),
                               f2bf(b1.x), f2bf(b1.y), f2bf(b1.z), f2bf(b1.w)};
        *(uint4*)&Bs[row * 40 + kc] = *(uint4*)q;
      }
      __syncthreads();
      s8v af[4], bfg[4];
      for (int f = 0; f < 4; f++) {
        af[f]  = *(const s8v*)&As[(wm + f * 16 + r16) * 40 + kg * 8];
        bfg[f] = *(const s8v*)&Bs[(wn + f * 16 + r16) * 40 + kg * 8];
      }
      for (int i = 0; i < 4; i++)
        for (int j = 0; j < 4; j++)
          acc[i][j] = mfma_bf16(af[i], bfg[j], acc[i][j]);
      __syncthreads();
    }

    int rbase = (lane >> 4) * 4;
    for (int j = 0; j < 4; j++) {
      int n = n0 + wn + j * 16 + r16;
      float bv = 0.f;
      if (bias1) bv += bias1[n];
      if (bias2) bv += bias2[n];
      for (int i = 0; i < 4; i++) {
        for (int r = 0; r < 4; r++) {
          int m = m0 + wm + i * 16 + rbase + r;
          if (m < M) {
            float v = acc[i][j][r] + bv;
            if (mode == 0) {
              Cf[(long)m * ldc + n] = v;
            } else {
              int bb = m / Tl, tt = m - bb * Tl;
              Cf[(long)(bb * 128 + tt + 1) * ldc + n] = v;
            }
          }
        }
      }
    }
    __syncthreads();
  }
}

// ---------------- LSTM recurrence ----------------
// grid 121; workers at blockIdx%8==0 (16). Worker blk owns units [blk*16,+16).
// Wave g computes gate g for 16 units x 16 batches via MFMA; Whh hi/lo
// fragments persistent in VGPRs (3-term product with h hi/lo split, three
// independent accumulator chains).
// hsync element = packed uint: bf16(h) in hi 16 bits, bf16(h - hi) in lo.
// hsync is pre-filled with SENTINEL; a valid packed h can never equal it
// (hi 0xFFFF would be NaN and h is always finite). The store of h is the
// only synchronization: consumers spin directly on their own h-words.
__global__ __launch_bounds__(256) void lstm_recur(
    const float* __restrict__ P,              // [16*Tl][1024], rows b*Tl+t
    const unsigned short* __restrict__ WhhH,  // [1024][256] bf16 hi
    const unsigned short* __restrict__ WhhL,  // [1024][256] bf16 lo
    unsigned int* __restrict__ hsync,         // [Tl][16][256] packed hi|lo
    const unsigned int* __restrict__ hinit,   // [16][256] packed, or null
    const float* __restrict__ cinit,          // [16][256] or null
    unsigned short* __restrict__ hout, int ldo, int coloff,
    float* __restrict__ cfin, int Tl) {
  int widx = (int)blockIdx.x;
  if (widx & 7) return;                       // keep workers on XCD0 (L2 share)
  int blk = widx >> 3;                        // 0..15
  __shared__ unsigned short hh[16 * 264];
  __shared__ unsigned short hl[16 * 264];
  __shared__ float gbuf[4][16][16];
  int tid = threadIdx.x;
  int lane = tid & 63, gate = tid >> 6;
  int U = blk * 16;
  int r16 = lane & 15, kg = lane >> 4;

  s8v wfh[8], wfl[8];
  {
    long roff = (long)(gate * 256 + U + r16) * 256 + kg * 8;
    for (int kt = 0; kt < 8; kt++) {
      wfh[kt] = *(const s8v*)(WhhH + roff + kt * 32);
      wfl[kt] = *(const s8v*)(WhhL + roff + kt * 32);
    }
  }
  int b = tid >> 4, u = tid & 15;
  float c = cinit ? cinit[b * 256 + U + u] : 0.f;

  for (int t = 0; t < Tl; t++) {
    // P loads first: no dependency on h, overlap with the poll.
    const float* prow = P + (size_t)(b * Tl + t) * 1024 + U + u;
    float p0 = prow[0], p1 = prow[256], p2 = prow[512], p3 = prow[768];
    if (t > 0) {
      // ---- data-is-flag: spin until all 16 rows of column tid are valid ----
      const unsigned int* hp = hsync + (size_t)(t - 1) * 4096;
      unsigned int uv[16];
      for (;;) {
        bool ok = true;
#pragma unroll
        for (int i = 0; i < 16; i++)
          uv[i] = __hip_atomic_load(hp + i * 256 + tid, __ATOMIC_RELAXED,
                                    __HIP_MEMORY_SCOPE_AGENT);
#pragma unroll
        for (int i = 0; i < 16; i++) ok &= (uv[i] != SENTINEL);
        if (ok) break;
        __builtin_amdgcn_s_sleep(1);          // backoff off the fast path
      }
#pragma unroll
      for (int i = 0; i < 16; i++) {
        hh[i * 264 + tid] = (unsigned short)(uv[i] >> 16);
        hl[i * 264 + tid] = (unsigned short)(uv[i] & 0xFFFFu);
      }
    } else {
      for (int i = 0; i < 16; i++) {
        unsigned int uvv = hinit ? hinit[i * 256 + tid] : 0u;
        hh[i * 264 + tid] = (unsigned short)(uvv >> 16);
        hl[i * 264 + tid] = (unsigned short)(uvv & 0xFFFFu);
      }
    }
    __syncthreads();                          // LDS hh/hl ready
    // three independent accumulator chains (ah*Wh, al*Wh, ah*Wl)
    f4v a0 = (f4v){0.f, 0.f, 0.f, 0.f};
    f4v a1 = (f4v){0.f, 0.f, 0.f, 0.f};
    f4v a2 = (f4v){0.f, 0.f, 0.f, 0.f};
#pragma unroll
    for (int kt = 0; kt < 8; kt++) {
      s8v ah = *(const s8v*)&hh[r16 * 264 + kt * 32 + kg * 8];
      s8v al = *(const s8v*)&hl[r16 * 264 + kt * 32 + kg * 8];
      a0 = mfma_bf16(ah, wfh[kt], a0);
      a1 = mfma_bf16(al, wfh[kt], a1);
      a2 = mfma_bf16(ah, wfl[kt], a2);
    }
#pragma unroll
    for (int r = 0; r < 4; r++)
      gbuf[gate][kg * 4 + r][r16] = a0[r] + a1[r] + a2[r];
    __syncthreads();                          // gbuf ready; also fences hh reuse
    float gi = gbuf[0][b][u] + p0;
    float gf = gbuf[1][b][u] + p1;
    float gg = gbuf[2][b][u] + p2;
    float go = gbuf[3][b][u] + p3;
    c = sigm(gf) * c + sigm(gi) * tanh_f(gg);
    float h = sigm(go) * tanh_f(c);
    unsigned short hb = f2bf(h);
    unsigned int packed =
        ((unsigned int)hb << 16) | (unsigned int)f2bf(h - bf2f(hb));
    // the ONLY sync: data store doubles as the flag (buffer pre-sentineled)
    __hip_atomic_store(hsync + (size_t)t * 4096 + b * 256 + U + u, packed,
                       __ATOMIC_RELAXED, __HIP_MEMORY_SCOPE_AGENT);
    hout[(size_t)(b * Tl + t) * ldo + coloff + U + u] = hb;
  }
  if (cfin) cfin[b * 256 + U + u] = c;
}

// ---------------- attention: scores + softmax + context ----------------
__global__ __launch_bounds__(256) void attn_ctx(
    const float* __restrict__ dp,             // [2032][256] (includes attn_b)
    const float* __restrict__ ep,             // [2048][256]
    const float* __restrict__ vw,             // [256]
    const unsigned int* __restrict__ enc_out, // [128][16][256] packed hi|lo
    unsigned short* __restrict__ Acat)        // [2032][512], write cols 256..511
{
  __shared__ float sdp[256], sv[256], sc[128];
  int bt = blockIdx.x;
  int b = bt / DLEN;
  int tid = threadIdx.x;
  sdp[tid] = dp[(long)bt * 256 + tid];
  sv[tid] = vw[tid];
  __syncthreads();
  int lane = tid & 63, wid = tid >> 6;
  for (int i = 0; i < 32; i++) {
    int s = wid * 32 + i;
    float4 e4 = *(const float4*)&ep[(long)(b * 128 + s) * 256 + lane * 4];
    int h0 = lane * 4;
    float part = sv[h0] * tanh_f(sdp[h0] + e4.x);
    part += sv[h0 + 1] * tanh_f(sdp[h0 + 1] + e4.y);
    part += sv[h0 + 2] * tanh_f(sdp[h0 + 2] + e4.z);
    part += sv[h0 + 3] * tanh_f(sdp[h0 + 3] + e4.w);
    for (int off = 32; off >= 1; off >>= 1) part += __shfl_xor(part, off);
    if (lane == 0) sc[s] = part;
  }
  __syncthreads();
  if (wid == 0) {
    float a0 = sc[lane], a1 = sc[lane + 64];
    float mx = fmaxf(a0, a1);
    for (int off = 32; off >= 1; off >>= 1) mx = fmaxf(mx, __shfl_xor(mx, off));
    float e0 = __expf(a0 - mx), e1 = __expf(a1 - mx);
    float sm = e0 + e1;
    for (int off = 32; off >= 1; off >>= 1) sm += __shfl_xor(sm, off);
    float inv = 1.0f / sm;
    sc[lane] = e0 * inv;
    sc[lane + 64] = e1 * inv;
  }
  __syncthreads();
  float acc = 0.f;
  for (int s = 0; s < 128; s++) {
    unsigned int uv = enc_out[(long)(s * 16 + b) * 256 + tid];
    float hv = bf2f((unsigned short)(uv >> 16)) +
               bf2f((unsigned short)(uv & 0xFFFFu));
    acc += sc[s] * hv;
  }
  Acat[(long)bt * 512 + 256 + tid] = f2bf(acc);
}

// ---------------------------------------------------------------------------
extern "C" void kernel_launch(void* const* d_in, const int* in_sizes, int n_in,
                              void* d_out, int out_size, void* d_ws, size_t ws_size,
                              hipStream_t stream) {
  (void)in_sizes; (void)n_in; (void)out_size; (void)ws_size;
  const int* src = (const int*)d_in[0];
  const int* tgt = (const int*)d_in[1];
  auto F32 = [&](int i) { return (const float*)d_in[i]; };
  const float* enc_emb = F32(2);
  const float* dec_emb = F32(3);
  // enc l0: 4..7 (Wih,Whh,bih,bhh), enc l1: 8..11, dec l0: 12..15, dec l1: 16..19
  const float* attnW = F32(20);
  const float* attnB = F32(21);
  const float* vw = F32(22);
  const float* outW = F32(23);
  const float* outB = F32(24);
  float* out = (float*)d_out;

  // ---- bulk scratch inside d_out (dead before final logits/zero writes) ----
  float* Pf0 = out;                        // 2,097,152 f each
  float* Pf1 = Pf0 + 2097152;
  float* Pf2 = Pf1 + 2097152;
  float* Pf3 = Pf2 + 2097152;
  unsigned int* hs0 = (unsigned int*)(Pf3 + 2097152);  // 524,288 u32 each
  unsigned int* hs1 = hs0 + 524288;
  unsigned int* hs2 = hs1 + 524288;
  unsigned int* hs3 = hs2 + 524288;
  float* dpf = (float*)(hs3 + 524288);     // 524,288 f (uses 520,192)
  float* epf = dpf + 524288;               // 524,288 f
  unsigned short* WHB = (unsigned short*)(epf + 524288);  // 4 x (hi+lo) 524,288
  unsigned short* WhhH[4], *WhhL[4];
  for (int l = 0; l < 4; l++) {
    WhhH[l] = WHB + (size_t)l * 524288;
    WhhL[l] = WHB + (size_t)l * 524288 + 262144;
  }
  unsigned short* XB = WHB + (size_t)4 * 524288;          // 5 x 524,288 shorts
  unsigned short* Xe  = XB;
  unsigned short* X2  = XB + 524288;
  unsigned short* Xd  = XB + 2 * 524288;
  unsigned short* Xd2 = XB + 3 * 524288;
  unsigned short* Ebf = XB + 4 * 524288;
  // total: ~13.9M floats << 65.5M floats of d_out

  // ---- minimal d_ws usage (live during logits GEMM) ----
  char* w = (char*)d_ws;
  unsigned short* Acat = (unsigned short*)w;              // 2,080,768 B
  float* cfin = (float*)(w + 2097152 + 4096);             // 2*4096*4 B
  float* cfin0 = cfin, *cfin1 = cfin + 4096;

  // sentinel-fill all 4 hsync buffers (data-is-flag sync): 8 MB of 0xFF
  hipMemsetAsync(hs0, 0xFF, (size_t)4 * 524288 * 4, stream);
  // weight hi/lo splits (Whh of the 4 layer-runs: in[5],[9],[13],[17])
  whh_split4<<<4096, 256, 0, stream>>>(F32(5), F32(9), F32(13), F32(17), WHB);
  gather_rows<<<2048, 64, 0, stream>>>(src, enc_emb, Xe, 0);
  gather_rows<<<2032, 64, 0, stream>>>(tgt, dec_emb, Xd, 1);
  // P-GEMMs: enc0 now, dec0 hoisted (independent of encoder chain)
  gemm_bt<<<dim3(8, 16), 256, 0, stream>>>(Xe, 256, F32(4), 256, 2048, 256,
      F32(6), F32(7), Pf0, 1024, 0, 0, 1);
  gemm_bt<<<dim3(8, 16), 256, 0, stream>>>(Xd, 256, F32(12), 256, 2032, 256,
      F32(14), F32(15), Pf2, 1024, 0, 0, 1);
  // encoder layer 0
  lstm_recur<<<121, 256, 0, stream>>>(Pf0, WhhH[0], WhhL[0], hs0,
      nullptr, nullptr, X2, 256, 0, cfin0, 128);
  // encoder layer 1
  gemm_bt<<<dim3(8, 16), 256, 0, stream>>>(X2, 256, F32(8), 256, 2048, 256,
      F32(10), F32(11), Pf1, 1024, 0, 0, 1);
  lstm_recur<<<121, 256, 0, stream>>>(Pf1, WhhH[1], WhhL[1], hs1,
      nullptr, nullptr, Ebf, 256, 0, cfin1, 128);
  // decoder layer 0 (init = enc layer0 finals; P already computed)
  lstm_recur<<<121, 256, 0, stream>>>(Pf2, WhhH[2], WhhL[2], hs2,
      hs0 + (size_t)127 * 4096, cfin0, Xd2, 256, 0, nullptr, 127);
  // decoder layer 1 (init = enc layer1 finals); h -> Acat cols 0..255
  gemm_bt<<<dim3(8, 16), 256, 0, stream>>>(Xd2, 256, F32(16), 256, 2032, 256,
      F32(18), F32(19), Pf3, 1024, 0, 0, 1);
  lstm_recur<<<121, 256, 0, stream>>>(Pf3, WhhH[3], WhhL[3], hs3,
      hs1 + (size_t)127 * 4096, cfin1, Acat, 512, 0, nullptr, 127);
  // attention projections: dp = dec_out@Wd^T + attn_b ; ep = enc_out@We^T
  gemm_bt<<<dim3(2, 16), 256, 0, stream>>>(Acat, 512, attnW, 512, 2032, 256,
      attnB, nullptr, dpf, 256, 0, 0, 1);
  gemm_bt<<<dim3(2, 16), 256, 0, stream>>>(Ebf, 256, attnW + 256, 512, 2048, 256,
      nullptr, nullptr, epf, 256, 0, 0, 1);
  attn_ctx<<<2032, 256, 0, stream>>>(dpf, epf, vw, hs1, Acat);
  // ---- final writes: every element of d_out is overwritten from here ----
  gemm_bt<<<dim3(250, 4), 256, 0, stream>>>(Acat, 512, outW, 512, 2032, 512,
      outB, nullptr, out, NVOC, 1, 127, 4);
  zero_t0<<<500, 256, 0, stream>>>(out);
}

// Round 4
// 1333.437 us; speedup vs baseline: 7.0283x; 1.4688x over previous
//
#include <hip/hip_runtime.h>

// ---------------------------------------------------------------------------
// Seq2Seq LSTM (B=16, H=256, L=2, S=128, T=128, V=32000).
// Inputs fp32 (per reference dtypes), output fp32. Internal compute: bf16 MFMA
// with fp32 accumulation; h and Whh use hi/lo bf16 splits for fp32-class
// accuracy in the recurrence; x and Wih single bf16 (matches prior GEMM path).
//
// v4: ALL FOUR layer-runs fused into ONE persistent pipelined kernel
// (lstm_pipe): 64 worker blocks = 4 layers x 16 unit-slices. Layer l consumes
// layer l-1's h stream directly (sentinel-polled packed u32), computing
// x@Wih^T as a 4th MFMA chain in-step — the per-layer P GEMMs are gone.
// Encoder layers 0/1 overlap (stagger 1 step); decoder layers 2/3 start when
// enc finals (sentineled cfin + h[127]) appear, then overlap too.
// Serialized step-count: 4x128 -> ~2x129.
//
// Sync remains v3's data-is-flag: buffers pre-filled with 0xFFFFFFFF (packed
// bf16-hi of finite h can never be 0xFFFF; fp32 c is never that NaN bit
// pattern); producers issue ONE relaxed agent-scope store; consumers spin on
// their own words. No acquire/release/fence cache maintenance anywhere.
// Layer l's 16 workers land on XCD l via blockIdx%8 (locality only;
// correctness is placement-independent).
// ---------------------------------------------------------------------------

typedef __attribute__((ext_vector_type(8))) short s8v;
typedef __attribute__((ext_vector_type(8))) __bf16 bf8v;
typedef __attribute__((ext_vector_type(4))) float f4v;

#define HDIM 256
#define DLEN 127
#define NVOC 32000
#define SENTINEL 0xFFFFFFFFu

__device__ __forceinline__ float bf2f(unsigned short u) {
  union { unsigned int i; float f; } v; v.i = ((unsigned int)u) << 16; return v.f;
}
__device__ __forceinline__ unsigned short f2bf(float x) {
  union { float f; unsigned int i; } v; v.f = x;
  unsigned int u = v.i;
  return (unsigned short)((u + 0x7FFFu + ((u >> 16) & 1u)) >> 16);
}
__device__ __forceinline__ float sigm(float x) {
  x = fminf(fmaxf(x, -30.f), 30.f);
  return 1.f / (1.f + __expf(-x));
}
__device__ __forceinline__ float tanh_f(float x) {
  float y = fminf(fmaxf(x, -15.f), 15.f);
  float e = __expf(2.f * y);
  return (e - 1.f) / (e + 1.f);
}
__device__ __forceinline__ f4v mfma_bf16(s8v a, s8v b, f4v c) {
  return __builtin_amdgcn_mfma_f32_16x16x32_bf16(
      __builtin_bit_cast(bf8v, a), __builtin_bit_cast(bf8v, b), c, 0, 0, 0);
}

// sentinel column poll: load h[i][tid] for i=0..15 until all valid
#define POLLCOL(base)                                                         \
  for (;;) {                                                                  \
    bool ok = true;                                                           \
    _Pragma("unroll") for (int i = 0; i < 16; i++)                            \
        uv[i] = __hip_atomic_load((base) + i * 256 + tid, __ATOMIC_RELAXED,   \
                                  __HIP_MEMORY_SCOPE_AGENT);                  \
    _Pragma("unroll") for (int i = 0; i < 16; i++) ok &= (uv[i] != SENTINEL); \
    if (ok) break;                                                            \
    __builtin_amdgcn_s_sleep(1);                                              \
  }

// ------------- split 4 fp32 Whh matrices into bf16 hi + lo -------------
// grid 4096: blocks [l*1024,(l+1)*1024) -> layer-run l.
// HB + l*524288 = hi[262144] then lo[262144].
__global__ __launch_bounds__(256) void whh_split4(
    const float* __restrict__ W0, const float* __restrict__ W1,
    const float* __restrict__ W2, const float* __restrict__ W3,
    unsigned short* __restrict__ HB) {
  int l = blockIdx.x >> 10;
  int i = (blockIdx.x & 1023) * 256 + threadIdx.x;
  const float* W = (l == 0) ? W0 : (l == 1) ? W1 : (l == 2) ? W2 : W3;
  float w = W[i];
  unsigned short h = f2bf(w);
  unsigned short* Hh = HB + (size_t)l * 524288;
  Hh[i] = h;
  Hh[262144 + i] = f2bf(w - bf2f(h));
}

// ------------- split 4 fp32 Wih matrices into single bf16 -------------
__global__ __launch_bounds__(256) void wih_split4(
    const float* __restrict__ W0, const float* __restrict__ W1,
    const float* __restrict__ W2, const float* __restrict__ W3,
    unsigned short* __restrict__ WIB) {
  int l = blockIdx.x >> 10;
  int i = (blockIdx.x & 1023) * 256 + threadIdx.x;
  const float* W = (l == 0) ? W0 : (l == 1) ? W1 : (l == 2) ? W2 : W3;
  WIB[(size_t)l * 262144 + i] = f2bf(W[i]);
}

// ------------- bsum[l][n] = bih_l[n] + bhh_l[n], n in [0,1024) -------------
__global__ __launch_bounds__(256) void bias_sum(
    const float* __restrict__ b0i, const float* __restrict__ b0h,
    const float* __restrict__ b1i, const float* __restrict__ b1h,
    const float* __restrict__ b2i, const float* __restrict__ b2h,
    const float* __restrict__ b3i, const float* __restrict__ b3h,
    float* __restrict__ out) {
  int i = blockIdx.x * 256 + threadIdx.x;       // grid 16 -> 4096
  int l = i >> 10, n = i & 1023;
  const float* bi = (l == 0) ? b0i : (l == 1) ? b1i : (l == 2) ? b2i : b3i;
  const float* bh = (l == 0) ? b0h : (l == 1) ? b1h : (l == 2) ? b2h : b3h;
  out[i] = bi[n] + bh[n];
}

// ---------------- embedding gather: fp32 emb -> bf16 rows ----------------
__global__ __launch_bounds__(64) void gather_rows(
    const int* __restrict__ toks, const float* __restrict__ emb,
    unsigned short* __restrict__ out, int dec) {
  int r = blockIdx.x, tid = threadIdx.x;
  int token = dec ? toks[(r / DLEN) * 128 + (r % DLEN)] : toks[r];
  float4 v = *(const float4*)&emb[(long)token * HDIM + tid * 4];
  unsigned short q[4] = {f2bf(v.x), f2bf(v.y), f2bf(v.z), f2bf(v.w)};
  *(uint2*)&out[(long)r * HDIM + tid * 4] = *(uint2*)q;
}

// ---------------- zero first timestep of output (fp32) ----------------
__global__ __launch_bounds__(256) void zero_t0(float* __restrict__ out) {
  int i = blockIdx.x * 256 + threadIdx.x;      // grid 500 -> 128000
  int b = i / 8000, off = (i - b * 8000) * 4;
  float4 z = {0.f, 0.f, 0.f, 0.f};
  *(float4*)&out[(long)b * 128 * NVOC + off] = z;
}

// ---------------- GEMM: C = A(MxK,bf16) @ B(NxK,fp32)^T + bias ----------------
// mode 0: fp32 out Cf (ldc). mode 1: fp32 out, row m -> row (m/Tl)*128+(m%Tl)+1.
__global__ __launch_bounds__(256) void gemm_bt(
    const unsigned short* __restrict__ A, int lda,
    const float* __restrict__ B, int ldb,
    int M, int K,
    const float* __restrict__ bias1, const float* __restrict__ bias2,
    float* __restrict__ Cf, int ldc, int mode, int Tl, int miters) {
  __shared__ unsigned short As[128 * 40];
  __shared__ unsigned short Bs[128 * 40];
  int tid = threadIdx.x;
  int lane = tid & 63, wid = tid >> 6;
  int wm = (wid >> 1) * 64, wn = (wid & 1) * 64;
  int r16 = lane & 15, kg = lane >> 4;
  int n0 = blockIdx.x * 128;

  for (int mi = 0; mi < miters; mi++) {
    int m0 = (blockIdx.y * miters + mi) * 128;
    f4v acc[4][4];
    for (int i = 0; i < 4; i++)
      for (int j = 0; j < 4; j++) acc[i][j] = (f4v){0.f, 0.f, 0.f, 0.f};

    for (int k0 = 0; k0 < K; k0 += 32) {
      for (int i = 0; i < 2; i++) {
        int idx = tid + i * 256;
        int row = idx >> 2, kc = (idx & 3) * 8;
        uint4 va = {0u, 0u, 0u, 0u};
        int gm = m0 + row;
        if (gm < M) va = *(const uint4*)&A[(long)gm * lda + k0 + kc];
        *(uint4*)&As[row * 40 + kc] = va;
        const float* bp = &B[(long)(n0 + row) * ldb + k0 + kc];
        float4 b0 = *(const float4*)bp, b1 = *(const float4*)(bp + 4);
        unsigned short q[8] = {f2bf(b0.x), f2bf(b0.y), f2bf(b0.z), f2bf(b0.w),
                               f2bf(b1.x), f2bf(b1.y), f2bf(b1.z), f2bf(b1.w)};
        *(uint4*)&Bs[row * 40 + kc] = *(uint4*)q;
      }
      __syncthreads();
      s8v af[4], bfg[4];
      for (int f = 0; f < 4; f++) {
        af[f]  = *(const s8v*)&As[(wm + f * 16 + r16) * 40 + kg * 8];
        bfg[f] = *(const s8v*)&Bs[(wn + f * 16 + r16) * 40 + kg * 8];
      }
      for (int i = 0; i < 4; i++)
        for (int j = 0; j < 4; j++)
          acc[i][j] = mfma_bf16(af[i], bfg[j], acc[i][j]);
      __syncthreads();
    }

    int rbase = (lane >> 4) * 4;
    for (int j = 0; j < 4; j++) {
      int n = n0 + wn + j * 16 + r16;
      float bv = 0.f;
      if (bias1) bv += bias1[n];
      if (bias2) bv += bias2[n];
      for (int i = 0; i < 4; i++) {
        for (int r = 0; r < 4; r++) {
          int m = m0 + wm + i * 16 + rbase + r;
          if (m < M) {
            float v = acc[i][j][r] + bv;
            if (mode == 0) {
              Cf[(long)m * ldc + n] = v;
            } else {
              int bb = m / Tl, tt = m - bb * Tl;
              Cf[(long)(bb * 128 + tt + 1) * ldc + n] = v;
            }
          }
        }
      }
    }
    __syncthreads();
  }
}

// ---------------- fused pipelined 4-layer LSTM ----------------
// grid 124; worker iff (widx&7)<4 && (widx>>3)<16. layer = widx&7 (-> XCD),
// blk = widx>>3 owns units [blk*16,+16) of that layer.
// Per step, per wave (gate): 4 MFMA chains of 8: x@Wih, h_hi@Whh_hi,
// h_lo@Whh_hi, h_hi@Whh_lo; weights persistent in VGPRs (24 s8v).
// x source: layer0/2 -> gathered embeddings (global bf16, loaded early);
// layer1/3 -> prev layer's hsync (sentinel poll, take bf16 hi).
// Own recurrence via own hsync (packed hi|lo) exactly as v3.
// Decoder init: poll sentineled cfin (fp32 bits) + enc hsync slot 127.
__global__ __launch_bounds__(256) void lstm_pipe(
    const unsigned short* __restrict__ WIB,   // [4][1024][256] bf16
    const unsigned short* __restrict__ WHB,   // [4][hi 262144 | lo 262144]
    const float* __restrict__ bsum,           // [4][1024] bih+bhh
    const unsigned short* __restrict__ Xe,    // [16*128][256] bf16
    const unsigned short* __restrict__ Xd,    // [16*127][256] bf16
    unsigned int* __restrict__ hsA,           // [4][128][16][256] packed
    unsigned int* __restrict__ cfinA,         // [2][4096] fp32 bits, sentineled
    unsigned short* __restrict__ Ebf,         // enc1 h out, [16*128][256] bf16
    unsigned short* __restrict__ Acat) {      // dec1 h out, [2032][512] cols 0..255
  int widx = (int)blockIdx.x;
  int layer = widx & 7;
  int blk = widx >> 3;
  if (layer > 3 || blk > 15) return;
  __shared__ unsigned short xx[16 * 264];
  __shared__ unsigned short hh[16 * 264];
  __shared__ unsigned short hl[16 * 264];
  __shared__ float gbuf[4][16][16];
  int tid = threadIdx.x;
  int lane = tid & 63, gate = tid >> 6;
  int U = blk * 16;
  int r16 = lane & 15, kg = lane >> 4;
  int Tl = (layer < 2) ? 128 : 127;
  unsigned int* own = hsA + (size_t)layer * 524288;
  const unsigned int* prevb = (layer & 1) ? own - 524288 : nullptr;
  const unsigned short* Xg = (layer == 0) ? Xe : (layer == 2) ? Xd : nullptr;
  const unsigned int* hini =
      (layer >= 2) ? hsA + (size_t)(layer - 2) * 524288 + (size_t)127 * 4096
                   : nullptr;
  unsigned int* cini = (layer >= 2) ? cfinA + (size_t)(layer - 2) * 4096 : nullptr;
  unsigned int* cout = (layer < 2) ? cfinA + (size_t)layer * 4096 : nullptr;
  unsigned short* hout = (layer == 1) ? Ebf : (layer == 3) ? Acat : nullptr;
  int ldo = (layer == 3) ? 512 : 256;

  s8v wfi[8], wfh[8], wfl[8];
  {
    const unsigned short* wi = WIB + (size_t)layer * 262144;
    const unsigned short* wh = WHB + (size_t)layer * 524288;
    const unsigned short* wl = wh + 262144;
    long roff = (long)(gate * 256 + U + r16) * 256 + kg * 8;
    for (int kt = 0; kt < 8; kt++) {
      wfi[kt] = *(const s8v*)(wi + roff + kt * 32);
      wfh[kt] = *(const s8v*)(wh + roff + kt * 32);
      wfl[kt] = *(const s8v*)(wl + roff + kt * 32);
    }
  }
  int b = tid >> 4, u = tid & 15;
  float bb0 = bsum[layer * 1024 + U + u];
  float bb1 = bsum[layer * 1024 + 256 + U + u];
  float bb2 = bsum[layer * 1024 + 512 + U + u];
  float bb3 = bsum[layer * 1024 + 768 + U + u];
  float c;
  if (cini) {
    unsigned int cw;
    for (;;) {
      cw = __hip_atomic_load(cini + b * 256 + U + u, __ATOMIC_RELAXED,
                             __HIP_MEMORY_SCOPE_AGENT);
      if (cw != SENTINEL) break;
      __builtin_amdgcn_s_sleep(8);            // long wait: enc still running
    }
    union { unsigned int i; float f; } cv; cv.i = cw; c = cv.f;
  } else {
    c = 0.f;
  }

  for (int t = 0; t < Tl; t++) {
    unsigned int uv[16];
    unsigned short xr[16];
    if (Xg) {                                  // issue x loads early (no dep)
#pragma unroll
      for (int i = 0; i < 16; i++)
        xr[i] = Xg[((size_t)(i * Tl + t)) * 256 + tid];
    }
    // own-h (or decoder init) poll -> hh/hl
    const unsigned int* hbase = (t > 0) ? own + (size_t)(t - 1) * 4096 : hini;
    if (hbase) {
      POLLCOL(hbase)
#pragma unroll
      for (int i = 0; i < 16; i++) {
        hh[i * 264 + tid] = (unsigned short)(uv[i] >> 16);
        hl[i * 264 + tid] = (unsigned short)(uv[i] & 0xFFFFu);
      }
    } else {
#pragma unroll
      for (int i = 0; i < 16; i++) { hh[i * 264 + tid] = 0; hl[i * 264 + tid] = 0; }
    }
    // x -> xx (prev layer runs ~1 step ahead: poll normally instant)
    if (Xg) {
#pragma unroll
      for (int i = 0; i < 16; i++) xx[i * 264 + tid] = xr[i];
    } else {
      POLLCOL(prevb + (size_t)t * 4096)
#pragma unroll
      for (int i = 0; i < 16; i++)
        xx[i * 264 + tid] = (unsigned short)(uv[i] >> 16);
    }
    __syncthreads();                           // LDS tiles ready
    f4v a0 = (f4v){0.f, 0.f, 0.f, 0.f};
    f4v a1 = a0, a2 = a0, a3 = a0;
#pragma unroll
    for (int kt = 0; kt < 8; kt++) {
      s8v xv = *(const s8v*)&xx[r16 * 264 + kt * 32 + kg * 8];
      s8v ah = *(const s8v*)&hh[r16 * 264 + kt * 32 + kg * 8];
      s8v al = *(const s8v*)&hl[r16 * 264 + kt * 32 + kg * 8];
      a3 = mfma_bf16(xv, wfi[kt], a3);
      a0 = mfma_bf16(ah, wfh[kt], a0);
      a1 = mfma_bf16(al, wfh[kt], a1);
      a2 = mfma_bf16(ah, wfl[kt], a2);
    }
#pragma unroll
    for (int r = 0; r < 4; r++)
      gbuf[gate][kg * 4 + r][r16] = a0[r] + a1[r] + a2[r] + a3[r];
    __syncthreads();                           // gbuf ready; fences LDS reuse
    float gi = gbuf[0][b][u] + bb0;
    float gf = gbuf[1][b][u] + bb1;
    float gg = gbuf[2][b][u] + bb2;
    float go = gbuf[3][b][u] + bb3;
    c = sigm(gf) * c + sigm(gi) * tanh_f(gg);
    float h = sigm(go) * tanh_f(c);
    unsigned short hb = f2bf(h);
    unsigned int packed =
        ((unsigned int)hb << 16) | (unsigned int)f2bf(h - bf2f(hb));
    __hip_atomic_store(own + (size_t)t * 4096 + b * 256 + U + u, packed,
                       __ATOMIC_RELAXED, __HIP_MEMORY_SCOPE_AGENT);
    if (hout) hout[(size_t)(b * Tl + t) * ldo + U + u] = hb;
  }
  if (cout) {
    union { float f; unsigned int i; } cv; cv.f = c;
    __hip_atomic_store(cout + b * 256 + U + u, cv.i, __ATOMIC_RELAXED,
                       __HIP_MEMORY_SCOPE_AGENT);
  }
}

// ---------------- attention: scores + softmax + context ----------------
__global__ __launch_bounds__(256) void attn_ctx(
    const float* __restrict__ dp,             // [2032][256] (includes attn_b)
    const float* __restrict__ ep,             // [2048][256]
    const float* __restrict__ vw,             // [256]
    const unsigned int* __restrict__ enc_out, // [128][16][256] packed hi|lo
    unsigned short* __restrict__ Acat)        // [2032][512], write cols 256..511
{
  __shared__ float sdp[256], sv[256], sc[128];
  int bt = blockIdx.x;
  int b = bt / DLEN;
  int tid = threadIdx.x;
  sdp[tid] = dp[(long)bt * 256 + tid];
  sv[tid] = vw[tid];
  __syncthreads();
  int lane = tid & 63, wid = tid >> 6;
  for (int i = 0; i < 32; i++) {
    int s = wid * 32 + i;
    float4 e4 = *(const float4*)&ep[(long)(b * 128 + s) * 256 + lane * 4];
    int h0 = lane * 4;
    float part = sv[h0] * tanh_f(sdp[h0] + e4.x);
    part += sv[h0 + 1] * tanh_f(sdp[h0 + 1] + e4.y);
    part += sv[h0 + 2] * tanh_f(sdp[h0 + 2] + e4.z);
    part += sv[h0 + 3] * tanh_f(sdp[h0 + 3] + e4.w);
    for (int off = 32; off >= 1; off >>= 1) part += __shfl_xor(part, off);
    if (lane == 0) sc[s] = part;
  }
  __syncthreads();
  if (wid == 0) {
    float a0 = sc[lane], a1 = sc[lane + 64];
    float mx = fmaxf(a0, a1);
    for (int off = 32; off >= 1; off >>= 1) mx = fmaxf(mx, __shfl_xor(mx, off));
    float e0 = __expf(a0 - mx), e1 = __expf(a1 - mx);
    float sm = e0 + e1;
    for (int off = 32; off >= 1; off >>= 1) sm += __shfl_xor(sm, off);
    float inv = 1.0f / sm;
    sc[lane] = e0 * inv;
    sc[lane + 64] = e1 * inv;
  }
  __syncthreads();
  float acc = 0.f;
  for (int s = 0; s < 128; s++) {
    unsigned int uv = enc_out[(long)(s * 16 + b) * 256 + tid];
    float hv = bf2f((unsigned short)(uv >> 16)) +
               bf2f((unsigned short)(uv & 0xFFFFu));
    acc += sc[s] * hv;
  }
  Acat[(long)bt * 512 + 256 + tid] = f2bf(acc);
}

// ---------------------------------------------------------------------------
extern "C" void kernel_launch(void* const* d_in, const int* in_sizes, int n_in,
                              void* d_out, int out_size, void* d_ws, size_t ws_size,
                              hipStream_t stream) {
  (void)in_sizes; (void)n_in; (void)out_size; (void)ws_size;
  const int* src = (const int*)d_in[0];
  const int* tgt = (const int*)d_in[1];
  auto F32 = [&](int i) { return (const float*)d_in[i]; };
  const float* enc_emb = F32(2);
  const float* dec_emb = F32(3);
  // enc l0: 4..7 (Wih,Whh,bih,bhh), enc l1: 8..11, dec l0: 12..15, dec l1: 16..19
  const float* attnW = F32(20);
  const float* attnB = F32(21);
  const float* vw = F32(22);
  const float* outW = F32(23);
  const float* outB = F32(24);
  float* out = (float*)d_out;

  // ---- bulk scratch inside d_out (dead before final logits/zero writes) ----
  unsigned int* hsA = (unsigned int*)out;                 // 4 x 524,288 u32
  float* dpf = (float*)(hsA + (size_t)4 * 524288);        // 524,288 f
  float* epf = dpf + 524288;                              // 524,288 f
  unsigned short* WHB = (unsigned short*)(epf + 524288);  // 4 x 524,288 u16
  unsigned short* WIB = WHB + (size_t)4 * 524288;         // 4 x 262,144 u16
  unsigned short* Xe  = WIB + (size_t)4 * 262144;         // 524,288 u16
  unsigned short* Xd  = Xe + 524288;                      // 524,288 u16
  unsigned short* Ebf = Xd + 524288;                      // 524,288 u16
  float* bsum = (float*)(Ebf + 524288);                   // 4,096 f
  // total ~ 5.8M float-equivalents << 65.5M floats of d_out

  // ---- minimal d_ws usage (live during logits GEMM) ----
  char* w = (char*)d_ws;
  unsigned short* Acat = (unsigned short*)w;              // 2,080,768 B
  unsigned int* cfinA = (unsigned int*)(w + 2097152 + 4096);  // 2 x 4096 u32

  // sentinel fills (data-is-flag sync; re-poisoned every launch)
  hipMemsetAsync(hsA, 0xFF, (size_t)4 * 524288 * 4, stream);
  hipMemsetAsync(cfinA, 0xFF, (size_t)2 * 4096 * 4, stream);
  // weight preprocessing
  whh_split4<<<4096, 256, 0, stream>>>(F32(5), F32(9), F32(13), F32(17), WHB);
  wih_split4<<<4096, 256, 0, stream>>>(F32(4), F32(8), F32(12), F32(16), WIB);
  bias_sum<<<16, 256, 0, stream>>>(F32(6), F32(7), F32(10), F32(11),
                                   F32(14), F32(15), F32(18), F32(19), bsum);
  gather_rows<<<2048, 64, 0, stream>>>(src, enc_emb, Xe, 0);
  gather_rows<<<2032, 64, 0, stream>>>(tgt, dec_emb, Xd, 1);
  // the whole 4-layer recurrence pipeline in one dispatch
  lstm_pipe<<<124, 256, 0, stream>>>(WIB, WHB, bsum, Xe, Xd, hsA, cfinA,
                                     Ebf, Acat);
  // attention projections: dp = dec_out@Wd^T + attn_b ; ep = enc_out@We^T
  gemm_bt<<<dim3(2, 16), 256, 0, stream>>>(Acat, 512, attnW, 512, 2032, 256,
      attnB, nullptr, dpf, 256, 0, 0, 1);
  gemm_bt<<<dim3(2, 16), 256, 0, stream>>>(Ebf, 256, attnW + 256, 512, 2048, 256,
      nullptr, nullptr, epf, 256, 0, 0, 1);
  attn_ctx<<<2032, 256, 0, stream>>>(dpf, epf, vw, hsA + 524288, Acat);
  // ---- final writes: every element of d_out is overwritten from here ----
  gemm_bt<<<dim3(250, 4), 256, 0, stream>>>(Acat, 512, outW, 512, 2032, 512,
      outB, nullptr, out, NVOC, 1, 127, 4);
  zero_t0<<<500, 256, 0, stream>>>(out);
}